// Round 2
// baseline (128.338 us; speedup 1.0000x reference)
//
#include <hip/hip_runtime.h>
#include <hip/hip_bf16.h>

// HybridLoss: focal + contrastive + 0.1*graph_reg.  N=8192, D=128.
// Contrastive split algebraically:
//   same-label pairs: sum sq = 2*n_c*S_c - 2*||sum_c f||^2  (O(N*D), exact)
//   diff-label pairs: relu(1 - dist)^2, nonzero only if sq<1 -> MFMA Gram +
//     cheap min-scan; exact slow path only if any pair has sq<1 (never for this data).

#define N_PTS 8192
#define DIM 128

typedef __bf16 bf16x8 __attribute__((ext_vector_type(8)));
typedef float f32x4 __attribute__((ext_vector_type(4)));

// workspace layout (bytes)
#define FBF_OFF   0                            // __bf16[8192*128] = 2 MB
#define SQN_OFF   (N_PTS * DIM * 2)            // float[8192]
#define CPART_OFF (SQN_OFF + N_PTS * 4)        // float[2080*4]
#define FPART_OFF (CPART_OFF + 8320 * 4)       // float[32]
#define GPART_OFF (FPART_OFF + 32 * 4)         // float[256]
#define VPART_OFF (GPART_OFF + 256 * 4)        // float[128*256]

// ================= fused aux: prep(bf16+sqn+class sums) / focal / graph =========
__global__ __launch_bounds__(256) void aux_kernel(const float* __restrict__ feat,
                                                  const float* __restrict__ preds,
                                                  const float* __restrict__ targets,
                                                  const float* __restrict__ gfeat,
                                                  __bf16* __restrict__ fbf,
                                                  float* __restrict__ sqn,
                                                  float* __restrict__ vpart,
                                                  float* __restrict__ f_part,
                                                  float* __restrict__ g_part) {
    __shared__ float smem[1024];
    const int bx = blockIdx.x;
    const int tid = threadIdx.x;
    const int w = tid >> 6;
    const int lane = tid & 63;

    if (bx < 128) {
        // ---- prep: 64 rows per block; bf16 copy, sqn, per-class column sums ----
        float sx = 0.f, sy = 0.f, c1x = 0.f, c1y = 0.f;
        #pragma unroll
        for (int it = 0; it < 16; ++it) {
            const int r = bx * 64 + it * 4 + w;
            const float2 v = *reinterpret_cast<const float2*>(feat + r * DIM + lane * 2);
            const float t = targets[r];
            union { __bf16 h[2]; unsigned u; } pk;
            pk.h[0] = (__bf16)v.x; pk.h[1] = (__bf16)v.y;
            reinterpret_cast<unsigned*>(fbf)[r * (DIM / 2) + lane] = pk.u;
            float s = v.x * v.x + v.y * v.y;
            #pragma unroll
            for (int off = 32; off > 0; off >>= 1) s += __shfl_down(s, off);
            if (lane == 0) sqn[r] = s;
            sx += v.x; sy += v.y;
            c1x += t * v.x; c1y += t * v.y;
        }
        smem[w * 256 + 2 * lane]       = sx - c1x;   // class 0, dims 2L,2L+1
        smem[w * 256 + 2 * lane + 1]   = sy - c1y;
        smem[w * 256 + 128 + 2 * lane]     = c1x;    // class 1
        smem[w * 256 + 128 + 2 * lane + 1] = c1y;
        __syncthreads();
        vpart[bx * 256 + tid] = smem[tid] + smem[256 + tid] + smem[512 + tid] + smem[768 + tid];
    } else if (bx < 160) {
        // ---- focal partials ----
        const int b = bx - 128;
        const int i = b * 256 + tid;
        const float p = preds[i], t = targets[i];
        const float bce = fmaxf(p, 0.f) - p * t + log1pf(expf(-fabsf(p)));
        const float pt = expf(-bce);
        const float om = 1.f - pt;
        float v = 0.25f * om * om * bce;
        #pragma unroll
        for (int off = 32; off > 0; off >>= 1) v += __shfl_down(v, off);
        if (lane == 0) smem[w] = v;
        __syncthreads();
        if (tid == 0) f_part[b] = smem[0] + smem[1] + smem[2] + smem[3];
    } else {
        // ---- graph regularizer partials ----
        const int b = bx - 160;
        float acc = 0.f;
        #pragma unroll
        for (int it = 0; it < 8; ++it) {
            const int r = b * 4 + w + it * 1024;
            if (r < N_PTS - 1) {
                const float2 a = *reinterpret_cast<const float2*>(gfeat + r * DIM + lane * 2);
                const float2 bb = *reinterpret_cast<const float2*>(gfeat + (r + 1) * DIM + lane * 2);
                const float dx = bb.x - a.x, dy = bb.y - a.y;
                float s = dx * dx + dy * dy;
                #pragma unroll
                for (int off = 32; off > 0; off >>= 1) s += __shfl_down(s, off);
                if (lane == 0) acc += sqrtf(s);
            }
        }
        if (lane == 0) smem[w] = acc;
        __syncthreads();
        if (tid == 0) g_part[b] = smem[0] + smem[1] + smem[2] + smem[3];
    }
}

// ================= pair kernel: MFMA Gram + margin min-scan ======================
template<bool DIAG>
__device__ __forceinline__ float scan_min(const f32x4 (&acc)[4][4],
                                          const f32x4 (&sqni)[4], const f32x4 (&ti4)[4],
                                          const float (&sqnj)[4], const float (&tj4)[4],
                                          int wm, int wn, int quad, int m15) {
    float minkey = 1e30f;
    #pragma unroll
    for (int tm = 0; tm < 4; ++tm) {
        #pragma unroll
        for (int tn = 0; tn < 4; ++tn) {
            const int jl = wn * 64 + tn * 16 + m15;
            #pragma unroll
            for (int e = 0; e < 4; ++e) {
                const float sq = sqni[tm][e] + sqnj[tn] - 2.f * acc[tm][tn][e];
                bool excl = (ti4[tm][e] == tj4[tn]);
                if (DIAG) {
                    const int il = wm * 64 + tm * 16 + quad * 4 + e;
                    excl = excl || (jl <= il);
                }
                minkey = fminf(minkey, excl ? 1e30f : sq);
            }
        }
    }
    return minkey;
}

template<bool DIAG>
__device__ __forceinline__ float scan_slow(const f32x4 (&acc)[4][4],
                                           const f32x4 (&sqni)[4], const f32x4 (&ti4)[4],
                                           const float (&sqnj)[4], const float (&tj4)[4],
                                           int wm, int wn, int quad, int m15) {
    float lsum = 0.f;
    #pragma unroll
    for (int tm = 0; tm < 4; ++tm) {
        #pragma unroll
        for (int tn = 0; tn < 4; ++tn) {
            const int jl = wn * 64 + tn * 16 + m15;
            #pragma unroll
            for (int e = 0; e < 4; ++e) {
                const float sq = sqni[tm][e] + sqnj[tn] - 2.f * acc[tm][tn][e];
                bool excl = (ti4[tm][e] == tj4[tn]);
                if (DIAG) {
                    const int il = wm * 64 + tm * 16 + quad * 4 + e;
                    excl = excl || (jl <= il);
                }
                if (!excl && sq < 1.f) {
                    const float d = sqrtf(fmaxf(sq, 0.f));
                    const float m = 1.f - d;
                    lsum += 2.f * m * m;     // off-diag block or strict-upper: weight 2
                }
            }
        }
    }
    return lsum;
}

__global__ __launch_bounds__(256, 2) void pair_kernel(const __bf16* __restrict__ fbf,
                                                      const float* __restrict__ sqn,
                                                      const float* __restrict__ targets,
                                                      float* __restrict__ c_part) {
    // decode upper-tri block index u -> (bi, bj), bi <= bj
    const int u = blockIdx.x;
    const int v = 2079 - u;
    int k = (int)((sqrtf(8.f * (float)v + 1.f) - 1.f) * 0.5f);
    while ((k + 1) * (k + 2) / 2 <= v) ++k;
    while (k * (k + 1) / 2 > v) --k;
    const int bi = 63 - k;
    const int bj = 63 - (v - k * (k + 1) / 2);

    const int tid = threadIdx.x;
    const int lane = tid & 63;
    const int wv = tid >> 6;
    const int quad = lane >> 4;
    const int m15 = lane & 15;
    const int wm = wv >> 1, wn = wv & 1;
    const int ibase = bi * 128, jbase = bj * 128;

    // fragment loads straight from global (L2-resident 2 MB)
    const char* fb = reinterpret_cast<const char*>(fbf);
    const char* arow = fb + (size_t)(ibase + wm * 64 + m15) * 256 + quad * 16;
    const char* brow = fb + (size_t)(jbase + wn * 64 + m15) * 256 + quad * 16;
    bf16x8 af[4][4], bfr[4][4];       // [t][ks]
    #pragma unroll
    for (int t = 0; t < 4; ++t)
        #pragma unroll
        for (int ks = 0; ks < 4; ++ks) {
            af[t][ks]  = *reinterpret_cast<const bf16x8*>(arow + t * 4096 + ks * 64);
            bfr[t][ks] = *reinterpret_cast<const bf16x8*>(brow + t * 4096 + ks * 64);
        }

    f32x4 acc[4][4];
    #pragma unroll
    for (int a = 0; a < 4; ++a)
        #pragma unroll
        for (int b = 0; b < 4; ++b) acc[a][b] = (f32x4){0.f, 0.f, 0.f, 0.f};

    #pragma unroll
    for (int ks = 0; ks < 4; ++ks)
        #pragma unroll
        for (int tm = 0; tm < 4; ++tm)
            #pragma unroll
            for (int tn = 0; tn < 4; ++tn)
                acc[tm][tn] = __builtin_amdgcn_mfma_f32_16x16x32_bf16(
                    af[tm][ks], bfr[tn][ks], acc[tm][tn], 0, 0, 0);

    // epilogue inputs
    f32x4 sqni[4], ti4[4];
    float sqnj[4], tj4[4];
    #pragma unroll
    for (int tm = 0; tm < 4; ++tm) {
        const int i0 = wm * 64 + tm * 16 + quad * 4;
        sqni[tm] = *reinterpret_cast<const f32x4*>(sqn + ibase + i0);
        ti4[tm]  = *reinterpret_cast<const f32x4*>(targets + ibase + i0);
    }
    #pragma unroll
    for (int tn = 0; tn < 4; ++tn) {
        const int jl = wn * 64 + tn * 16 + m15;
        sqnj[tn] = sqn[jbase + jl];
        tj4[tn]  = targets[jbase + jl];
    }

    const bool diag = (bi == bj);
    const float minkey = diag
        ? scan_min<true >(acc, sqni, ti4, sqnj, tj4, wm, wn, quad, m15)
        : scan_min<false>(acc, sqni, ti4, sqnj, tj4, wm, wn, quad, m15);

    float lsum = 0.f;
    if (minkey < 1.f)
        lsum = diag
            ? scan_slow<true >(acc, sqni, ti4, sqnj, tj4, wm, wn, quad, m15)
            : scan_slow<false>(acc, sqni, ti4, sqnj, tj4, wm, wn, quad, m15);

    float wsum = 0.f;
    if (__any(minkey < 1.f)) {
        #pragma unroll
        for (int off = 32; off > 0; off >>= 1) lsum += __shfl_down(lsum, off);
        wsum = lsum;
    }
    if (lane == 0) c_part[u * 4 + wv] = wsum;
}

// ================= finalize =====================================================
__global__ __launch_bounds__(256) void finalize_kernel(const float* __restrict__ c_part,
                                                       const float* __restrict__ f_part,
                                                       const float* __restrict__ g_part,
                                                       const float* __restrict__ vpart,
                                                       const float* __restrict__ sqn,
                                                       const float* __restrict__ targets,
                                                       float* __restrict__ out) {
    __shared__ float red[32];
    const int tid = threadIdx.x;
    const int w = tid >> 6, lane = tid & 63;

    float c = 0.f;
    for (int i = tid; i < 8320; i += 256) c += c_part[i];
    float f = (tid < 32) ? f_part[tid] : 0.f;
    float g = g_part[tid];

    float V = 0.f;
    for (int b = 0; b < 128; ++b) V += vpart[b * 256 + tid];
    float vsq = V * V;                 // tid<128: class 0; else class 1

    float stot = 0.f, s1 = 0.f, n1 = 0.f;
    for (int i = tid; i < N_PTS; i += 256) {
        const float s = sqn[i], t = targets[i];
        stot += s; s1 += t * s; n1 += t;
    }

    #pragma unroll
    for (int off = 32; off > 0; off >>= 1) {
        c += __shfl_down(c, off);
        f += __shfl_down(f, off);
        g += __shfl_down(g, off);
        vsq  += __shfl_down(vsq, off);
        stot += __shfl_down(stot, off);
        s1   += __shfl_down(s1, off);
        n1   += __shfl_down(n1, off);
    }
    if (lane == 0) {
        red[w] = c; red[4 + w] = f; red[8 + w] = g;
        red[12 + w] = vsq; red[16 + w] = stot; red[20 + w] = s1; red[24 + w] = n1;
    }
    __syncthreads();
    if (tid == 0) {
        const double cs = (double)red[0] + red[1] + red[2] + red[3];
        const double fs = (double)red[4] + red[5] + red[6] + red[7];
        const double gs = (double)red[8] + red[9] + red[10] + red[11];
        const double v0sq = (double)red[12] + red[13];   // waves 0,1 = class 0
        const double v1sq = (double)red[14] + red[15];
        const double st = (double)red[16] + red[17] + red[18] + red[19];
        const double s1s = (double)red[20] + red[21] + red[22] + red[23];
        const double n1s = (double)red[24] + red[25] + red[26] + red[27];
        const double n0s = (double)N_PTS - n1s;
        const double s0s = st - s1s;
        const double same = 2.0 * (n0s * s0s - v0sq) + 2.0 * (n1s * s1s - v1sq);
        out[0] = (float)((cs + same) / ((double)N_PTS * N_PTS)
                         + fs / N_PTS + 0.1 * (gs / (N_PTS - 1)));
    }
}

extern "C" void kernel_launch(void* const* d_in, const int* in_sizes, int n_in,
                              void* d_out, int out_size, void* d_ws, size_t ws_size,
                              hipStream_t stream) {
    const float* preds    = (const float*)d_in[0];
    const float* targets  = (const float*)d_in[1];
    const float* features = (const float*)d_in[2];
    const float* gfeat    = (const float*)d_in[3];
    char* ws = (char*)d_ws;
    __bf16* fbf   = (__bf16*)(ws + FBF_OFF);
    float* sqn    = (float*)(ws + SQN_OFF);
    float* c_part = (float*)(ws + CPART_OFF);
    float* f_part = (float*)(ws + FPART_OFF);
    float* g_part = (float*)(ws + GPART_OFF);
    float* vpart  = (float*)(ws + VPART_OFF);
    float* out = (float*)d_out;

    aux_kernel<<<416, 256, 0, stream>>>(features, preds, targets, gfeat,
                                        fbf, sqn, vpart, f_part, g_part);
    pair_kernel<<<2080, 256, 0, stream>>>(fbf, sqn, targets, c_part);
    finalize_kernel<<<1, 256, 0, stream>>>(c_part, f_part, g_part, vpart, sqn, targets, out);
}